// Round 3
// baseline (2862.214 us; speedup 1.0000x reference)
//
#include <hip/hip_runtime.h>
#include <hip/hip_bf16.h>
#include <hip/hip_cooperative_groups.h>

namespace cg = cooperative_groups;

typedef __bf16 bf16;
typedef __attribute__((ext_vector_type(8))) __bf16 bf16x8;
typedef __attribute__((ext_vector_type(4))) float f32x4;

static __device__ __forceinline__ f32x4 MFMA(bf16x8 a, bf16x8 b, f32x4 c) {
  return __builtin_amdgcn_mfma_f32_16x16x32_bf16(a, b, c, 0, 0, 0);
}

__device__ __forceinline__ float sigm(float x) { return 1.0f / (1.0f + __expf(-x)); }
__device__ __forceinline__ float softplus_(float x) {
  return fmaxf(x, 0.0f) + log1pf(__expf(-fabsf(x)));
}

__device__ __forceinline__ void gl16(const bf16* g, char* l) {
  __builtin_amdgcn_global_load_lds(
      (const __attribute__((address_space(1))) char*)g,
      (__attribute__((address_space(3))) char*)l, 16, 0, 0);
}

// ---------------- conversion ----------------

__global__ void k_f32_to_bf16(const float* __restrict__ in, bf16* __restrict__ out, int n) {
  for (int i = blockIdx.x * blockDim.x + threadIdx.x; i < n; i += gridDim.x * blockDim.x)
    out[i] = (bf16)in[i];
}

// ---------------- fused 30-step GRU (cooperative) ----------------
// 384 blocks x 256 thr, 2 blocks/CU. Block tile: 128 rows x 32 j-cols x 3 gates.
// Wave tile: 64 rows x (16 j x 3 gates) -> 4 m-frags x 3 n-frags, 12 acc.
// A fragments: global->reg direct (no cross-wave reuse). B panel (96x64) via
// global_load_lds, double-buffered, counted vmcnt(11). Wi panel LDS-persistent.
__global__ __launch_bounds__(256, 2) void k_gru_all(
    const float* __restrict__ beliefs, bf16* __restrict__ hA, bf16* __restrict__ hB,
    const bf16* __restrict__ Wh, const bf16* __restrict__ Wi, const bf16* __restrict__ actB,
    const float* __restrict__ b_ih, const float* __restrict__ b_hh,
    const int* __restrict__ idx_i, const int* __restrict__ Kmat,
    bf16* __restrict__ states) {
  cg::grid_group grid = cg::this_grid();

  const int pid = blockIdx.x;
  const int xcd = pid & 7;
  const int q = pid >> 3;          // 0..47
  const int mt = q % 12;
  const int jhi = q / 12;          // 0..3
  const int m0 = mt * 128;
  const int j0 = (xcd * 4 + jhi) * 32;

  const int tid = threadIdx.x, wave = tid >> 6, lane = tid & 63;
  const int l15 = lane & 15;
  const int kgrp = lane >> 4;          // 0..3
  const int mhalf = wave & 1;          // row half (64)
  const int jsub = wave >> 1;          // j sub-tile of 16
  const int jlane = j0 + jsub * 16 + l15;

  __shared__ alignas(16) bf16 Bs[2][96][64];   // 24 KB dbuf (Wh panel)
  __shared__ alignas(16) bf16 WiS[96][64];     // 12 KB persistent (Wi panel)

  // staging lane decode (gl_lds: dst linear, src pre-swizzled)
  const int srow = lane >> 3;                       // 0..7
  const int scol = (((lane & 7) ^ srow) << 3);      // swizzled col (elems)

  const bf16* wsrc[3];
#pragma unroll
  for (int i = 0; i < 3; ++i) {
    int prow = wave * 24 + i * 8 + srow;            // 0..95
    int wrow = (prow >> 5) * 1024 + j0 + (prow & 31);
    wsrc[i] = Wh + (size_t)wrow * 1024 + scol;
  }

  auto stageB = [&](int buf, int kb) {
    char* dst = (char*)Bs + buf * 12288 + wave * 3072;
#pragma unroll
    for (int i = 0; i < 3; ++i) gl16(wsrc[i] + kb, dst + i * 1024);
  };

  // ---- one-time: init h0 (hA) + stage Wi panel ----
  const int n = m0 >> 8;
  const int i_n = idx_i[n];
  {
    for (int e = tid; e < 128 * 32; e += 256) {
      int rr = e >> 5, cc = e & 31;
      int m = m0 + rr, col = j0 + cc;
      hA[(size_t)m * 1024 + col] =
          (bf16)beliefs[((size_t)i_n * 256 + (m & 255)) * 1024 + col];
    }
#pragma unroll
    for (int i = 0; i < 3; ++i) {
      int prow = wave * 24 + i * 8 + srow;
      int wrow = (prow >> 5) * 1024 + j0 + (prow & 31);
      gl16(Wi + (size_t)wrow * 64 + scol, (char*)WiS + (wave * 24 + i * 8) * 128 + i * 0);
    }
  }
  asm volatile("s_waitcnt vmcnt(0)" ::: "memory");
  grid.sync();

  // hoisted epilogue constants
  const float br = b_ih[jlane] + b_hh[jlane];
  const float bz = b_ih[1024 + jlane] + b_hh[1024 + jlane];
  const float bin = b_ih[2048 + jlane];
  const float bhn = b_hh[2048 + jlane];
  const int k0 = Kmat[n * 4 + 0], k1 = Kmat[n * 4 + 1];
  const int k2 = Kmat[n * 4 + 2], k3 = Kmat[n * 4 + 3];

  const f32x4 zero = {0.f, 0.f, 0.f, 0.f};

  for (int s = 0; s < 30; ++s) {
    const bf16* hin = (s & 1) ? hB : hA;
    bf16* hout = (s & 1) ? hA : hB;
    const bf16* aBase = hin + (size_t)(m0 + mhalf * 64 + l15) * 1024 + (kgrp << 3);
    const bf16* actBase = actB + ((size_t)(i_n + s) * 256 + (m0 & 255) + mhalf * 64 + l15) * 64 + (kgrp << 3);

    f32x4 accR[4], accZ[4], accN[4], aIN[4];
#pragma unroll
    for (int f = 0; f < 4; ++f) { accR[f] = zero; accZ[f] = zero; accN[f] = zero; aIN[f] = zero; }

    bf16x8 aCur[8], aNxt[8];

    // prologue: stage B(0), load A(0)   [3 + 8 vmem in flight]
    stageB(0, 0);
#pragma unroll
    for (int f = 0; f < 8; ++f)
      aCur[f] = *(const bf16x8*)(aBase + (f & 3) * 16384 + ((f >> 2) << 5));

    for (int t = 0; t < 16; ++t) {
      if (t < 15) {
        stageB((t + 1) & 1, (t + 1) * 64);
#pragma unroll
        for (int f = 0; f < 8; ++f)
          aNxt[f] = *(const bf16x8*)(aBase + (f & 3) * 16384 + (t + 1) * 64 + ((f >> 2) << 5));
        asm volatile("s_waitcnt vmcnt(11)" ::: "memory");
      } else {
        // prefetch actions-A for the Wi iteration
#pragma unroll
        for (int f = 0; f < 8; ++f)
          aNxt[f] = *(const bf16x8*)(actBase + (f & 3) * 1024 + ((f >> 2) << 5));
        asm volatile("s_waitcnt vmcnt(8)" ::: "memory");
      }
      __builtin_amdgcn_s_barrier();

      const char* bb = (const char*)Bs + (t & 1) * 12288;
#pragma unroll
      for (int kkI = 0; kkI < 2; ++kkI) {
        const int kbyte = (((kkI << 5) + (kgrp << 3)) << 1) ^ ((l15 & 7) << 4);
        bf16x8 b0 = *(const bf16x8*)(bb + (jsub * 16 + l15) * 128 + kbyte);
        bf16x8 b1 = *(const bf16x8*)(bb + (32 + jsub * 16 + l15) * 128 + kbyte);
        bf16x8 b2 = *(const bf16x8*)(bb + (64 + jsub * 16 + l15) * 128 + kbyte);
#pragma unroll
        for (int mf = 0; mf < 4; ++mf) {
          accR[mf] = MFMA(aCur[kkI * 4 + mf], b0, accR[mf]);
          accZ[mf] = MFMA(aCur[kkI * 4 + mf], b1, accZ[mf]);
          accN[mf] = MFMA(aCur[kkI * 4 + mf], b2, accN[mf]);
        }
      }
      __builtin_amdgcn_sched_barrier(0);
      __builtin_amdgcn_s_barrier();
#pragma unroll
      for (int f = 0; f < 8; ++f) aCur[f] = aNxt[f];
    }

    // ---- iter 16: gi = actions @ Wi^T, B from persistent WiS ----
    {
      const char* bb = (const char*)WiS;
#pragma unroll
      for (int kkI = 0; kkI < 2; ++kkI) {
        const int kbyte = (((kkI << 5) + (kgrp << 3)) << 1) ^ ((l15 & 7) << 4);
        bf16x8 b0 = *(const bf16x8*)(bb + (jsub * 16 + l15) * 128 + kbyte);
        bf16x8 b1 = *(const bf16x8*)(bb + (32 + jsub * 16 + l15) * 128 + kbyte);
        bf16x8 b2 = *(const bf16x8*)(bb + (64 + jsub * 16 + l15) * 128 + kbyte);
#pragma unroll
        for (int mf = 0; mf < 4; ++mf) {
          accR[mf] = MFMA(aCur[kkI * 4 + mf], b0, accR[mf]);
          accZ[mf] = MFMA(aCur[kkI * 4 + mf], b1, accZ[mf]);
          aIN[mf]  = MFMA(aCur[kkI * 4 + mf], b2, aIN[mf]);
        }
      }
    }

    // ---- epilogue: gates + state update ----
#pragma unroll
    for (int mf = 0; mf < 4; ++mf) {
#pragma unroll
      for (int ii = 0; ii < 4; ++ii) {
        const int m = m0 + mhalf * 64 + mf * 16 + kgrp * 4 + ii;
        float rg = sigm(accR[mf][ii] + br);
        float zg = sigm(accZ[mf][ii] + bz);
        float ng = tanhf(aIN[mf][ii] + bin + rg * (accN[mf][ii] + bhn));
        float hp = (float)hin[(size_t)m * 1024 + jlane];
        float hnew = (1.0f - zg) * ng + zg * hp;
        bf16 hb = (bf16)hnew;
        hout[(size_t)m * 1024 + jlane] = hb;
        const int b = m & 255;
        if (k0 == s) states[((size_t)(n * 4 + 0) * 256 + b) * 1024 + jlane] = hb;
        if (k1 == s) states[((size_t)(n * 4 + 1) * 256 + b) * 1024 + jlane] = hb;
        if (k2 == s) states[((size_t)(n * 4 + 2) * 256 + b) * 1024 + jlane] = hb;
        if (k3 == s) states[((size_t)(n * 4 + 3) * 256 + b) * 1024 + jlane] = hb;
      }
    }

    grid.sync();
  }
}

// ---------------- generic GEMM: C = A(M x K) @ W(N x K)^T, fused epilogues ----------------
template <int EPI>
__global__ __launch_bounds__(256) void k_gemm_epi(
    const bf16* __restrict__ A, const bf16* __restrict__ W, int K, int Nreal, int ld_out,
    const float* __restrict__ bias, const bf16* __restrict__ resid,
    float* __restrict__ outF, bf16* __restrict__ outB) {
  const int m0 = blockIdx.x * 64;
  const int j0 = blockIdx.y * 64;
  const int tid = threadIdx.x, wave = tid >> 6, lane = tid & 63;
  __shared__ alignas(16) bf16 Al[64][72];
  __shared__ alignas(16) bf16 Wl[64][72];

  f32x4 acc[4];
  const f32x4 zero = {0.f, 0.f, 0.f, 0.f};
#pragma unroll
  for (int f = 0; f < 4; ++f) acc[f] = zero;

  const int r = tid >> 3, c8 = (tid & 7) << 3;
  const int arow = wave * 16 + (lane & 15);
  const int koff = (lane >> 4) << 3;

  for (int kb = 0; kb < K; kb += 64) {
    *(bf16x8*)&Al[r][c8]      = *(const bf16x8*)&A[(size_t)(m0 + r) * K + kb + c8];
    *(bf16x8*)&Al[r + 32][c8] = *(const bf16x8*)&A[(size_t)(m0 + r + 32) * K + kb + c8];
    int jr = j0 + r;      if (jr >= Nreal) jr = Nreal - 1;
    int jr2 = j0 + r + 32; if (jr2 >= Nreal) jr2 = Nreal - 1;
    *(bf16x8*)&Wl[r][c8]      = *(const bf16x8*)&W[(size_t)jr * K + kb + c8];
    *(bf16x8*)&Wl[r + 32][c8] = *(const bf16x8*)&W[(size_t)jr2 * K + kb + c8];
    __syncthreads();
#pragma unroll
    for (int kk = 0; kk < 64; kk += 32) {
      bf16x8 av = *(const bf16x8*)&Al[arow][kk + koff];
#pragma unroll
      for (int nf = 0; nf < 4; ++nf) {
        acc[nf] = MFMA(av, *(const bf16x8*)&Wl[nf * 16 + (lane & 15)][kk + koff], acc[nf]);
      }
    }
    __syncthreads();
  }

#pragma unroll
  for (int nf = 0; nf < 4; ++nf) {
    int j = j0 + nf * 16 + (lane & 15);
    float bj = (j < Nreal) ? bias[j] : 0.f;
#pragma unroll
    for (int i = 0; i < 4; ++i) {
      int m = m0 + wave * 16 + ((lane >> 4) << 2) + i;
      float v = acc[nf][i] + bj;
      if (EPI == 0) {
        outB[(size_t)m * ld_out + j] = (bf16)fmaxf(v, 0.f);
      } else if (EPI == 1) {
        v = fmaxf(v, 0.f) + (float)resid[(size_t)m * ld_out + j];
        outB[(size_t)m * ld_out + j] = (bf16)v;
      } else {
        if (j < Nreal) outF[(size_t)m * ld_out + j] = v;
      }
    }
  }
}

// ---------------- loss ----------------
__global__ __launch_bounds__(256) void k_loss_rows(
    const float* __restrict__ logits, const float* __restrict__ obs,
    const int* __restrict__ idx_i, const int* __restrict__ Kmat,
    float* __restrict__ partials) {
  const int row = blockIdx.x;
  const int n = row >> 10, g = (row >> 8) & 3, b = row & 255;
  const int i = idx_i[n], k = Kmat[n * 4 + g];
  const float* L = logits + (size_t)row * 814;
  const float* ob = obs + ((size_t)(k + i + 1) * 256 + b) * 16;
  const int tid = threadIdx.x, lane = tid & 63, wv = tid >> 6;
  __shared__ float red[4];

  float total = 0.f;
#pragma unroll
  for (int p = 0; p < 2; ++p) {
    const float* Lp = L + p * 407;
    const float* tg = ob + p * 8;
    float mx = -1e30f;
    for (int c = tid; c < 400; c += 256) mx = fmaxf(mx, Lp[c]);
#pragma unroll
    for (int s = 32; s; s >>= 1) mx = fmaxf(mx, __shfl_xor(mx, s));
    __syncthreads();
    if (lane == 0) red[wv] = mx;
    __syncthreads();
    mx = fmaxf(fmaxf(red[0], red[1]), fmaxf(red[2], red[3]));
    __syncthreads();
    float se = 0.f;
    for (int c = tid; c < 400; c += 256) se += __expf(Lp[c] - mx);
#pragma unroll
    for (int s = 32; s; s >>= 1) se += __shfl_xor(se, s);
    if (lane == 0) red[wv] = se;
    __syncthreads();
    se = red[0] + red[1] + red[2] + red[3];
    __syncthreads();

    if (tid == 0) {
      int cls = (int)tg[0];
      float lse = mx + logf(se);
      float v = lse - Lp[cls];
      float d0 = Lp[400] - tg[1], d1 = Lp[401] - tg[2];
      v += 0.5f * (d0 * d0 + d1 * d1);
      float s2 = softplus_(Lp[402]) - tg[3]; v += s2 * s2;
      float s3 = softplus_(Lp[403]) - tg[4]; v += s3 * s3;
      v += softplus_(Lp[404]) - Lp[404] * tg[5];
      v += softplus_(Lp[405]) - Lp[405] * tg[6];
      v += softplus_(Lp[406]) - Lp[406] * tg[7];
      total += v;
    }
    __syncthreads();
  }
  if (tid == 0) partials[row] = total * (1.0f / 1024.0f);
}

__global__ void k_reduce_final(const float* __restrict__ partials, float* __restrict__ out) {
  __shared__ float s[256];
  float v = 0.f;
  for (int i = threadIdx.x; i < 6144; i += 256) v += partials[i];
  s[threadIdx.x] = v;
  __syncthreads();
  for (int st = 128; st; st >>= 1) {
    if (threadIdx.x < st) s[threadIdx.x] += s[threadIdx.x + st];
    __syncthreads();
  }
  if (threadIdx.x == 0) out[0] = s[0];
}

// ---------------- launcher ----------------

extern "C" void kernel_launch(void* const* d_in, const int* in_sizes, int n_in,
                              void* d_out, int out_size, void* d_ws, size_t ws_size,
                              hipStream_t stream) {
  const float* obs      = (const float*)d_in[0];
  const float* actions  = (const float*)d_in[1];
  const float* beliefs  = (const float*)d_in[2];
  const float* w_ih     = (const float*)d_in[3];
  const float* w_hh     = (const float*)d_in[4];
  const float* b_ih     = (const float*)d_in[5];
  const float* b_hh     = (const float*)d_in[6];
  const float* pre_w1   = (const float*)d_in[7];
  const float* pre_b1   = (const float*)d_in[8];
  const float* pre_w2   = (const float*)d_in[9];
  const float* pre_b2   = (const float*)d_in[10];
  const float* dec_w    = (const float*)d_in[11];
  const float* dec_b    = (const float*)d_in[12];
  const int*   idx_i    = (const int*)d_in[13];
  const int*   Kmat     = (const int*)d_in[14];
  float* outF = (float*)d_out;

  char* p = (char*)d_ws;
  auto carve = [&](size_t bytes) {
    char* q = p;
    p += (bytes + 255) & ~(size_t)255;
    return q;
  };
  bf16* Wh      = (bf16*)carve(3072u * 1024u * 2u);
  bf16* Wi      = (bf16*)carve(3072u * 64u * 2u);
  bf16* actBv   = (bf16*)carve(128u * 256u * 64u * 2u);
  bf16* preW1b  = (bf16*)carve(64u * 1024u * 2u);
  bf16* preW2b  = (bf16*)carve(1024u * 64u * 2u);
  bf16* decWb   = (bf16*)carve(814u * 1024u * 2u);
  bf16* hA      = (bf16*)carve(1536u * 1024u * 2u);
  bf16* hB      = (bf16*)carve(1536u * 1024u * 2u);
  bf16* states  = (bf16*)carve(6144u * 1024u * 2u);
  bf16* h1      = (bf16*)carve(6144u * 64u * 2u);
  bf16* xbuf    = (bf16*)carve(6144u * 1024u * 2u);
  float* logits = (float*)carve((size_t)6144u * 814u * 4u);
  float* partials = (float*)carve(6144u * 4u);

  auto cvt = [&](const float* src, bf16* dst, int n) {
    int grid = (n + 255) / 256;
    if (grid > 4096) grid = 4096;
    k_f32_to_bf16<<<grid, 256, 0, stream>>>(src, dst, n);
  };
  cvt(w_hh, Wh, 3072 * 1024);
  cvt(w_ih, Wi, 3072 * 64);
  cvt(actions, actBv, 128 * 256 * 64);
  cvt(pre_w1, preW1b, 64 * 1024);
  cvt(pre_w2, preW2b, 1024 * 64);
  cvt(dec_w, decWb, 814 * 1024);

  // fused 30-step GRU (cooperative launch for grid.sync)
  {
    void* args[] = {(void*)&beliefs, (void*)&hA, (void*)&hB, (void*)&Wh, (void*)&Wi,
                    (void*)&actBv, (void*)&b_ih, (void*)&b_hh, (void*)&idx_i,
                    (void*)&Kmat, (void*)&states};
    hipLaunchCooperativeKernel((const void*)k_gru_all, dim3(384), dim3(256), args, 0, stream);
  }

  k_gemm_epi<0><<<dim3(96, 1), 256, 0, stream>>>(states, preW1b, 1024, 64, 64,
                                                 pre_b1, nullptr, nullptr, h1);
  k_gemm_epi<1><<<dim3(96, 16), 256, 0, stream>>>(h1, preW2b, 64, 1024, 1024,
                                                  pre_b2, states, nullptr, xbuf);
  k_gemm_epi<2><<<dim3(96, 13), 256, 0, stream>>>(xbuf, decWb, 1024, 814, 814,
                                                  dec_b, nullptr, logits, nullptr);

  k_loss_rows<<<6144, 256, 0, stream>>>(logits, obs, idx_i, Kmat, partials);
  k_reduce_final<<<1, 256, 0, stream>>>(partials, outF);
}

// Round 4
// 1434.668 us; speedup vs baseline: 1.9950x; 1.9950x over previous
//
#include <hip/hip_runtime.h>
#include <hip/hip_bf16.h>

typedef __bf16 bf16;
typedef __attribute__((ext_vector_type(8))) __bf16 bf16x8;
typedef __attribute__((ext_vector_type(4))) float f32x4;

static __device__ __forceinline__ f32x4 MFMA(bf16x8 a, bf16x8 b, f32x4 c) {
  return __builtin_amdgcn_mfma_f32_16x16x32_bf16(a, b, c, 0, 0, 0);
}

__device__ __forceinline__ float sigm(float x) { return 1.0f / (1.0f + __expf(-x)); }
__device__ __forceinline__ float softplus_(float x) {
  return fmaxf(x, 0.0f) + log1pf(__expf(-fabsf(x)));
}

__device__ __forceinline__ void gl16(const bf16* g, char* l) {
  __builtin_amdgcn_global_load_lds(
      (const __attribute__((address_space(1))) char*)g,
      (__attribute__((address_space(3))) char*)l, 16, 0, 0);
}

// ---------------- conversion & init ----------------

__global__ void k_f32_to_bf16(const float* __restrict__ in, bf16* __restrict__ out, int n) {
  for (int i = blockIdx.x * blockDim.x + threadIdx.x; i < n; i += gridDim.x * blockDim.x)
    out[i] = (bf16)in[i];
}

__global__ void k_init_h(const float* __restrict__ beliefs, const int* __restrict__ idx_i,
                         bf16* __restrict__ h) {
  int i = blockIdx.x * blockDim.x + threadIdx.x;
  int n = i >> 18;
  int rest = i & 262143;
  h[i] = (bf16)beliefs[(size_t)idx_i[n] * 262144 + rest];
}

// ---------------- GRU step v3 ----------------
// Grid 384 = 12 mt x 32 jt (jt = pid&31 -> all 12 same-jt blocks on XCD jt%8:
// Wh panel fetched once per XCD per step). Block: 128 M x 32 j x 3 gates.
// Wave: 64 M x 16 j x 3 gates -> 4 m-frags x 3 gate-frags.
// A (hin rows): global->reg direct, 3-deep prefetch, fully unrolled K-loop.
// B (Wh panel): LDS, 3 buffers, global_load_lds w16, XOR-swizzled source.
// Counted vmcnt keeps 2 iters of loads in flight across barriers.
__global__ __launch_bounds__(256, 2) void k_gru_step(
    const bf16* __restrict__ hin, bf16* __restrict__ hout,
    const bf16* __restrict__ Wh, const bf16* __restrict__ Wi,
    const bf16* __restrict__ actB,
    const float* __restrict__ b_ih, const float* __restrict__ b_hh,
    const int* __restrict__ idx_i, const int* __restrict__ Kmat,
    bf16* __restrict__ states, int step) {
  const int pid = blockIdx.x;
  const int mt = pid >> 5;        // 0..11
  const int jt = pid & 31;        // 0..31
  const int m0 = mt * 128;
  const int j0 = jt * 32;

  const int tid = threadIdx.x, wave = tid >> 6, lane = tid & 63;
  const int l15 = lane & 15;
  const int kgrp = lane >> 4;     // 0..3
  const int mhalf = wave & 1;     // row half of 64
  const int jsub = wave >> 1;     // j sub-tile of 16
  const int jlane = j0 + jsub * 16 + l15;

  __shared__ alignas(16) bf16 Bs[3][96][64];   // 3 x 12 KB

  // staging decode: 8 lanes per row, source col pre-swizzled (linear LDS dest)
  const int srow = lane >> 3;                      // 0..7
  const int scol = (((lane & 7) ^ srow) << 3);     // elems

  const bf16* wsrc[3];
  const bf16* wisrc[3];
#pragma unroll
  for (int i = 0; i < 3; ++i) {
    int prow = wave * 24 + i * 8 + srow;           // 0..95
    int wrow = (prow >> 5) * 1024 + j0 + (prow & 31);
    wsrc[i] = Wh + (size_t)wrow * 1024 + scol;
    wisrc[i] = Wi + (size_t)wrow * 64 + scol;
  }

  const int n = mt >> 1;
  const int i_n = idx_i[n];
  const bf16* aBase = hin + (size_t)(m0 + mhalf * 64 + l15) * 1024 + (kgrp << 3);
  const bf16* actBase =
      actB + ((size_t)(i_n + step) * 256 + (m0 & 255) + mhalf * 64 + l15) * 64 + (kgrp << 3);

  auto stageB = [&](int buf, int it) {
    char* dst = (char*)Bs + buf * 12288 + wave * 3072;
    if (it < 16) {
#pragma unroll
      for (int i = 0; i < 3; ++i) gl16(wsrc[i] + it * 64, dst + i * 1024);
    } else {
#pragma unroll
      for (int i = 0; i < 3; ++i) gl16(wisrc[i], dst + i * 1024);
    }
  };

  bf16x8 areg[3][8];
  auto loadA = [&](int bank, int it) {
    if (it < 16) {
#pragma unroll
      for (int f = 0; f < 8; ++f)
        areg[bank][f] =
            *(const bf16x8*)(aBase + (size_t)(f & 3) * 16384 + it * 64 + ((f >> 2) << 5));
    } else {
#pragma unroll
      for (int f = 0; f < 8; ++f)
        areg[bank][f] = *(const bf16x8*)(actBase + (f & 3) * 1024 + ((f >> 2) << 5));
    }
  };

  f32x4 accR[4], accZ[4], accNh[4], accNi[4];
  const f32x4 zero = {0.f, 0.f, 0.f, 0.f};
#pragma unroll
  for (int f = 0; f < 4; ++f) { accR[f] = zero; accZ[f] = zero; accNh[f] = zero; accNi[f] = zero; }

  auto compute = [&](int buf, int bank, f32x4 (&g2)[4]) {
    const char* bb = (const char*)Bs + buf * 12288;
#pragma unroll
    for (int kkI = 0; kkI < 2; ++kkI) {
      const int kbyte = (((kkI << 5) + (kgrp << 3)) << 1) ^ ((l15 & 7) << 4);
      bf16x8 b0 = *(const bf16x8*)(bb + (jsub * 16 + l15) * 128 + kbyte);
      bf16x8 b1 = *(const bf16x8*)(bb + (32 + jsub * 16 + l15) * 128 + kbyte);
      bf16x8 b2 = *(const bf16x8*)(bb + (64 + jsub * 16 + l15) * 128 + kbyte);
#pragma unroll
      for (int mf = 0; mf < 4; ++mf) {
        accR[mf] = MFMA(areg[bank][kkI * 4 + mf], b0, accR[mf]);
        accZ[mf] = MFMA(areg[bank][kkI * 4 + mf], b1, accZ[mf]);
        g2[mf] = MFMA(areg[bank][kkI * 4 + mf], b2, g2[mf]);
      }
    }
  };

  // prologue: slots 0,1 in flight (11 vmem each)
  stageB(0, 0); loadA(0, 0);
  stageB(1, 1); loadA(1, 1);

#pragma unroll
  for (int t = 0; t < 16; ++t) {
    if (t < 15) { stageB((t + 2) % 3, t + 2); loadA((t + 2) % 3, t + 2); }
    // drain slot t's B-staging: outstanding after it = A(t)8 + later slots
    if (t <= 14) asm volatile("s_waitcnt vmcnt(30)" ::: "memory");
    else         asm volatile("s_waitcnt vmcnt(19)" ::: "memory");
    __builtin_amdgcn_s_barrier();
    compute(t % 3, t % 3, accNh);
    __builtin_amdgcn_sched_barrier(0);
    __builtin_amdgcn_s_barrier();
  }
  // slot 16: gi = actions @ Wi^T (staged into buf 1 at t==14)
  asm volatile("s_waitcnt vmcnt(8)" ::: "memory");
  __builtin_amdgcn_s_barrier();
  compute(1, 1, accNi);

  // ---- epilogue: gates + state update ----
  const float br = b_ih[jlane] + b_hh[jlane];
  const float bz = b_ih[1024 + jlane] + b_hh[1024 + jlane];
  const float bin = b_ih[2048 + jlane];
  const float bhn = b_hh[2048 + jlane];
  const int k0 = Kmat[n * 4 + 0], k1 = Kmat[n * 4 + 1];
  const int k2 = Kmat[n * 4 + 2], k3 = Kmat[n * 4 + 3];
#pragma unroll
  for (int mf = 0; mf < 4; ++mf) {
#pragma unroll
    for (int ii = 0; ii < 4; ++ii) {
      const int m = m0 + mhalf * 64 + mf * 16 + kgrp * 4 + ii;
      float rg = sigm(accR[mf][ii] + br);
      float zg = sigm(accZ[mf][ii] + bz);
      float ng = tanhf(accNi[mf][ii] + bin + rg * (accNh[mf][ii] + bhn));
      float hp = (float)hin[(size_t)m * 1024 + jlane];
      float hnew = (1.0f - zg) * ng + zg * hp;
      bf16 hb = (bf16)hnew;
      hout[(size_t)m * 1024 + jlane] = hb;
      const int b = m & 255;
      if (k0 == step) states[((size_t)(n * 4 + 0) * 256 + b) * 1024 + jlane] = hb;
      if (k1 == step) states[((size_t)(n * 4 + 1) * 256 + b) * 1024 + jlane] = hb;
      if (k2 == step) states[((size_t)(n * 4 + 2) * 256 + b) * 1024 + jlane] = hb;
      if (k3 == step) states[((size_t)(n * 4 + 3) * 256 + b) * 1024 + jlane] = hb;
    }
  }
}

// ---------------- generic GEMM: C = A(M x K) @ W(N x K)^T, fused epilogues ----------------
template <int EPI>
__global__ __launch_bounds__(256) void k_gemm_epi(
    const bf16* __restrict__ A, const bf16* __restrict__ W, int K, int Nreal, int ld_out,
    const float* __restrict__ bias, const bf16* __restrict__ resid,
    float* __restrict__ outF, bf16* __restrict__ outB) {
  const int m0 = blockIdx.x * 64;
  const int j0 = blockIdx.y * 64;
  const int tid = threadIdx.x, wave = tid >> 6, lane = tid & 63;
  __shared__ alignas(16) bf16 Al[64][72];
  __shared__ alignas(16) bf16 Wl[64][72];

  f32x4 acc[4];
  const f32x4 zero = {0.f, 0.f, 0.f, 0.f};
#pragma unroll
  for (int f = 0; f < 4; ++f) acc[f] = zero;

  const int r = tid >> 3, c8 = (tid & 7) << 3;
  const int arow = wave * 16 + (lane & 15);
  const int koff = (lane >> 4) << 3;

  for (int kb = 0; kb < K; kb += 64) {
    *(bf16x8*)&Al[r][c8]      = *(const bf16x8*)&A[(size_t)(m0 + r) * K + kb + c8];
    *(bf16x8*)&Al[r + 32][c8] = *(const bf16x8*)&A[(size_t)(m0 + r + 32) * K + kb + c8];
    int jr = j0 + r;      if (jr >= Nreal) jr = Nreal - 1;
    int jr2 = j0 + r + 32; if (jr2 >= Nreal) jr2 = Nreal - 1;
    *(bf16x8*)&Wl[r][c8]      = *(const bf16x8*)&W[(size_t)jr * K + kb + c8];
    *(bf16x8*)&Wl[r + 32][c8] = *(const bf16x8*)&W[(size_t)jr2 * K + kb + c8];
    __syncthreads();
#pragma unroll
    for (int kk = 0; kk < 64; kk += 32) {
      bf16x8 av = *(const bf16x8*)&Al[arow][kk + koff];
#pragma unroll
      for (int nf = 0; nf < 4; ++nf) {
        acc[nf] = MFMA(av, *(const bf16x8*)&Wl[nf * 16 + (lane & 15)][kk + koff], acc[nf]);
      }
    }
    __syncthreads();
  }

#pragma unroll
  for (int nf = 0; nf < 4; ++nf) {
    int j = j0 + nf * 16 + (lane & 15);
    float bj = (j < Nreal) ? bias[j] : 0.f;
#pragma unroll
    for (int i = 0; i < 4; ++i) {
      int m = m0 + wave * 16 + ((lane >> 4) << 2) + i;
      float v = acc[nf][i] + bj;
      if (EPI == 0) {
        outB[(size_t)m * ld_out + j] = (bf16)fmaxf(v, 0.f);
      } else if (EPI == 1) {
        v = fmaxf(v, 0.f) + (float)resid[(size_t)m * ld_out + j];
        outB[(size_t)m * ld_out + j] = (bf16)v;
      } else {
        if (j < Nreal) outF[(size_t)m * ld_out + j] = v;
      }
    }
  }
}

// ---------------- loss ----------------
__global__ __launch_bounds__(256) void k_loss_rows(
    const float* __restrict__ logits, const float* __restrict__ obs,
    const int* __restrict__ idx_i, const int* __restrict__ Kmat,
    float* __restrict__ partials) {
  const int row = blockIdx.x;
  const int n = row >> 10, g = (row >> 8) & 3, b = row & 255;
  const int i = idx_i[n], k = Kmat[n * 4 + g];
  const float* L = logits + (size_t)row * 814;
  const float* ob = obs + ((size_t)(k + i + 1) * 256 + b) * 16;
  const int tid = threadIdx.x, lane = tid & 63, wv = tid >> 6;
  __shared__ float red[4];

  float total = 0.f;
#pragma unroll
  for (int p = 0; p < 2; ++p) {
    const float* Lp = L + p * 407;
    const float* tg = ob + p * 8;
    float mx = -1e30f;
    for (int c = tid; c < 400; c += 256) mx = fmaxf(mx, Lp[c]);
#pragma unroll
    for (int s = 32; s; s >>= 1) mx = fmaxf(mx, __shfl_xor(mx, s));
    __syncthreads();
    if (lane == 0) red[wv] = mx;
    __syncthreads();
    mx = fmaxf(fmaxf(red[0], red[1]), fmaxf(red[2], red[3]));
    __syncthreads();
    float se = 0.f;
    for (int c = tid; c < 400; c += 256) se += __expf(Lp[c] - mx);
#pragma unroll
    for (int s = 32; s; s >>= 1) se += __shfl_xor(se, s);
    if (lane == 0) red[wv] = se;
    __syncthreads();
    se = red[0] + red[1] + red[2] + red[3];
    __syncthreads();

    if (tid == 0) {
      int cls = (int)tg[0];
      float lse = mx + logf(se);
      float v = lse - Lp[cls];
      float d0 = Lp[400] - tg[1], d1 = Lp[401] - tg[2];
      v += 0.5f * (d0 * d0 + d1 * d1);
      float s2 = softplus_(Lp[402]) - tg[3]; v += s2 * s2;
      float s3 = softplus_(Lp[403]) - tg[4]; v += s3 * s3;
      v += softplus_(Lp[404]) - Lp[404] * tg[5];
      v += softplus_(Lp[405]) - Lp[405] * tg[6];
      v += softplus_(Lp[406]) - Lp[406] * tg[7];
      total += v;
    }
    __syncthreads();
  }
  if (tid == 0) partials[row] = total * (1.0f / 1024.0f);
}

__global__ void k_reduce_final(const float* __restrict__ partials, float* __restrict__ out) {
  __shared__ float s[256];
  float v = 0.f;
  for (int i = threadIdx.x; i < 6144; i += 256) v += partials[i];
  s[threadIdx.x] = v;
  __syncthreads();
  for (int st = 128; st; st >>= 1) {
    if (threadIdx.x < st) s[threadIdx.x] += s[threadIdx.x + st];
    __syncthreads();
  }
  if (threadIdx.x == 0) out[0] = s[0];
}

// ---------------- launcher ----------------

extern "C" void kernel_launch(void* const* d_in, const int* in_sizes, int n_in,
                              void* d_out, int out_size, void* d_ws, size_t ws_size,
                              hipStream_t stream) {
  const float* obs      = (const float*)d_in[0];
  const float* actions  = (const float*)d_in[1];
  const float* beliefs  = (const float*)d_in[2];
  const float* w_ih     = (const float*)d_in[3];
  const float* w_hh     = (const float*)d_in[4];
  const float* b_ih     = (const float*)d_in[5];
  const float* b_hh     = (const float*)d_in[6];
  const float* pre_w1   = (const float*)d_in[7];
  const float* pre_b1   = (const float*)d_in[8];
  const float* pre_w2   = (const float*)d_in[9];
  const float* pre_b2   = (const float*)d_in[10];
  const float* dec_w    = (const float*)d_in[11];
  const float* dec_b    = (const float*)d_in[12];
  const int*   idx_i    = (const int*)d_in[13];
  const int*   Kmat     = (const int*)d_in[14];
  float* outF = (float*)d_out;

  char* p = (char*)d_ws;
  auto carve = [&](size_t bytes) {
    char* q = p;
    p += (bytes + 255) & ~(size_t)255;
    return q;
  };
  bf16* Wh      = (bf16*)carve(3072u * 1024u * 2u);
  bf16* Wi      = (bf16*)carve(3072u * 64u * 2u);
  bf16* actBv   = (bf16*)carve(128u * 256u * 64u * 2u);
  bf16* preW1b  = (bf16*)carve(64u * 1024u * 2u);
  bf16* preW2b  = (bf16*)carve(1024u * 64u * 2u);
  bf16* decWb   = (bf16*)carve(814u * 1024u * 2u);
  bf16* hA      = (bf16*)carve(1536u * 1024u * 2u);
  bf16* hB      = (bf16*)carve(1536u * 1024u * 2u);
  bf16* states  = (bf16*)carve(6144u * 1024u * 2u);
  bf16* h1      = (bf16*)carve(6144u * 64u * 2u);
  bf16* xbuf    = (bf16*)carve(6144u * 1024u * 2u);
  float* logits = (float*)carve((size_t)6144u * 814u * 4u);
  float* partials = (float*)carve(6144u * 4u);

  auto cvt = [&](const float* src, bf16* dst, int n) {
    int grid = (n + 255) / 256;
    if (grid > 4096) grid = 4096;
    k_f32_to_bf16<<<grid, 256, 0, stream>>>(src, dst, n);
  };
  cvt(w_hh, Wh, 3072 * 1024);
  cvt(w_ih, Wi, 3072 * 64);
  cvt(actions, actBv, 128 * 256 * 64);
  cvt(pre_w1, preW1b, 64 * 1024);
  cvt(pre_w2, preW2b, 1024 * 64);
  cvt(dec_w, decWb, 814 * 1024);

  k_init_h<<<6144, 256, 0, stream>>>(beliefs, idx_i, hA);

  for (int t = 0; t < 30; ++t) {
    const bf16* hi = (t & 1) ? hB : hA;
    bf16* ho = (t & 1) ? hA : hB;
    k_gru_step<<<384, 256, 0, stream>>>(hi, ho, Wh, Wi, actBv, b_ih, b_hh,
                                        idx_i, Kmat, states, t);
  }

  k_gemm_epi<0><<<dim3(96, 1), 256, 0, stream>>>(states, preW1b, 1024, 64, 64,
                                                 pre_b1, nullptr, nullptr, h1);
  k_gemm_epi<1><<<dim3(96, 16), 256, 0, stream>>>(h1, preW2b, 64, 1024, 1024,
                                                  pre_b2, states, nullptr, xbuf);
  k_gemm_epi<2><<<dim3(96, 13), 256, 0, stream>>>(xbuf, decWb, 1024, 814, 814,
                                                  dec_b, nullptr, logits, nullptr);

  k_loss_rows<<<6144, 256, 0, stream>>>(logits, obs, idx_i, Kmat, partials);
  k_reduce_final<<<1, 256, 0, stream>>>(partials, outF);
}

// Round 5
// 737.796 us; speedup vs baseline: 3.8794x; 1.9445x over previous
//
#include <hip/hip_runtime.h>
#include <hip/hip_bf16.h>

typedef __bf16 bf16;
typedef __attribute__((ext_vector_type(8))) __bf16 bf16x8;
typedef __attribute__((ext_vector_type(4))) float f32x4;

static __device__ __forceinline__ f32x4 MFMA(bf16x8 a, bf16x8 b, f32x4 c) {
  return __builtin_amdgcn_mfma_f32_16x16x32_bf16(a, b, c, 0, 0, 0);
}

__device__ __forceinline__ float sigm(float x) { return 1.0f / (1.0f + __expf(-x)); }
__device__ __forceinline__ float softplus_(float x) {
  return fmaxf(x, 0.0f) + log1pf(__expf(-fabsf(x)));
}

__device__ __forceinline__ void gl16(const bf16* g, char* l) {
  __builtin_amdgcn_global_load_lds(
      (const __attribute__((address_space(1))) char*)g,
      (__attribute__((address_space(3))) char*)l, 16, 0, 0);
}

// ---------------- conversion & init ----------------

__global__ void k_f32_to_bf16(const float* __restrict__ in, bf16* __restrict__ out, int n) {
  for (int i = blockIdx.x * blockDim.x + threadIdx.x; i < n; i += gridDim.x * blockDim.x)
    out[i] = (bf16)in[i];
}

__global__ void k_init_h(const float* __restrict__ beliefs, const int* __restrict__ idx_i,
                         bf16* __restrict__ h) {
  int i = blockIdx.x * blockDim.x + threadIdx.x;
  int n = i >> 18;
  int rest = i & 262143;
  h[i] = (bf16)beliefs[(size_t)idx_i[n] * 262144 + rest];
}

// ---------------- GRU step v4 ----------------
// Grid 512 = 16 mt (96 rows) x 32 jt (32 j) -> exactly 2 blocks/CU (perfect balance).
// XCD = pid%8 = jt%8: each XCD owns 4 Wh panel slices (768 KB, L2-resident).
// Block: 96M x 32j x 3gates. Wave: 48M x 16j x 3g -> 3 m-frags x 3 gate-frags,
// 6 ds_read_b128 : 9 MFMA per kkI. A and B both LDS-staged (shared across waves).
// Triple-buffered: stage slot t+2 while computing t; counted vmcnt(12/6/0).
__global__ __launch_bounds__(256, 2) void k_gru_step(
    const bf16* __restrict__ hin, bf16* __restrict__ hout,
    const bf16* __restrict__ Wh, const bf16* __restrict__ Wi,
    const bf16* __restrict__ actB,
    const float* __restrict__ b_ih, const float* __restrict__ b_hh,
    const int* __restrict__ idx_i, const int* __restrict__ Kmat,
    bf16* __restrict__ states, int step) {
  const int pid = blockIdx.x;
  const int mt = pid >> 5;        // 0..15
  const int jt = pid & 31;        // 0..31  (XCD = jt%8)
  const int m0 = mt * 96;
  const int j0 = jt * 32;

  const int tid = threadIdx.x, wave = tid >> 6, lane = tid & 63;
  const int l15 = lane & 15;
  const int kgrp = lane >> 4;     // 0..3
  const int wm = wave >> 1;       // 0..1 : row half (48)
  const int wj = wave & 1;        // 0..1 : j half (16)
  const int jlane = j0 + wj * 16 + l15;

  __shared__ alignas(16) bf16 As[3][96][64];   // 3 x 12 KB
  __shared__ alignas(16) bf16 Bs[3][96][64];   // 3 x 12 KB  (rows = g*32 + jj)

  // staging decode: 8 rows per gl16, source col pre-swizzled (linear LDS dest)
  const int srow = lane >> 3;                      // 0..7
  const int scol = (((lane & 7) ^ srow) << 3);     // elems

  const bf16* asrc[3];   // hin rows
  const bf16* bsrc[3];   // Wh panel rows
  const bf16* aisrc[3];  // actions rows (slot 16)
  const bf16* bisrc[3];  // Wi panel rows (slot 16)
#pragma unroll
  for (int i = 0; i < 3; ++i) {
    const int prow = wave * 24 + i * 8 + srow;     // 0..95
    const int grow = m0 + prow;
    asrc[i] = hin + (size_t)grow * 1024 + scol;
    const int wr = (prow >> 5) * 1024 + j0 + (prow & 31);
    bsrc[i] = Wh + (size_t)wr * 1024 + scol;
    bisrc[i] = Wi + (size_t)wr * 64 + scol;
    const int np = grow >> 8;
    aisrc[i] = actB + ((size_t)(idx_i[np] + step) * 256 + (grow & 255)) * 64 + scol;
  }

  auto stage = [&](int buf, int it) {
    char* ad = (char*)As + buf * 12288 + (wave * 24) * 128;
    char* bd = (char*)Bs + buf * 12288 + (wave * 24) * 128;
    if (it < 16) {
#pragma unroll
      for (int i = 0; i < 3; ++i) {
        gl16(asrc[i] + it * 64, ad + i * 1024);
        gl16(bsrc[i] + it * 64, bd + i * 1024);
      }
    } else {
#pragma unroll
      for (int i = 0; i < 3; ++i) {
        gl16(aisrc[i], ad + i * 1024);
        gl16(bisrc[i], bd + i * 1024);
      }
    }
  };

  f32x4 accR[3], accZ[3], accNh[3], accNi[3];
  const f32x4 zero = {0.f, 0.f, 0.f, 0.f};
#pragma unroll
  for (int f = 0; f < 3; ++f) { accR[f] = zero; accZ[f] = zero; accNh[f] = zero; accNi[f] = zero; }

  // hoisted epilogue constants (scalar loads overlap the K loop)
  const float br = b_ih[jlane] + b_hh[jlane];
  const float bz = b_ih[1024 + jlane] + b_hh[1024 + jlane];
  const float bin = b_ih[2048 + jlane];
  const float bhn = b_hh[2048 + jlane];

  auto compute = [&](int buf, f32x4 (&gN)[3]) {
    const char* ab = (const char*)As + buf * 12288;
    const char* bb = (const char*)Bs + buf * 12288;
#pragma unroll
    for (int kkI = 0; kkI < 2; ++kkI) {
      const int kbyte = (((kkI << 5) + (kgrp << 3)) << 1) ^ ((l15 & 7) << 4);
      bf16x8 a0 = *(const bf16x8*)(ab + (wm * 48 + l15) * 128 + kbyte);
      bf16x8 a1 = *(const bf16x8*)(ab + (wm * 48 + 16 + l15) * 128 + kbyte);
      bf16x8 a2 = *(const bf16x8*)(ab + (wm * 48 + 32 + l15) * 128 + kbyte);
      bf16x8 b_r = *(const bf16x8*)(bb + (wj * 16 + l15) * 128 + kbyte);
      bf16x8 b_z = *(const bf16x8*)(bb + (32 + wj * 16 + l15) * 128 + kbyte);
      bf16x8 b_n = *(const bf16x8*)(bb + (64 + wj * 16 + l15) * 128 + kbyte);
      accR[0] = MFMA(a0, b_r, accR[0]);
      accR[1] = MFMA(a1, b_r, accR[1]);
      accR[2] = MFMA(a2, b_r, accR[2]);
      accZ[0] = MFMA(a0, b_z, accZ[0]);
      accZ[1] = MFMA(a1, b_z, accZ[1]);
      accZ[2] = MFMA(a2, b_z, accZ[2]);
      gN[0] = MFMA(a0, b_n, gN[0]);
      gN[1] = MFMA(a1, b_n, gN[1]);
      gN[2] = MFMA(a2, b_n, gN[2]);
    }
  };

  // prologue: slots 0,1 in flight (6 vmem each)
  stage(0, 0);
  stage(1, 1);

#pragma unroll
  for (int t = 0; t < 17; ++t) {
    if (t < 15) stage((t + 2) % 3, t + 2);
    if (t < 15)      asm volatile("s_waitcnt vmcnt(12)" ::: "memory");
    else if (t == 15) asm volatile("s_waitcnt vmcnt(6)" ::: "memory");
    else              asm volatile("s_waitcnt vmcnt(0)" ::: "memory");
    __builtin_amdgcn_s_barrier();
    if (t == 16) compute(16 % 3, accNi);
    else         compute(t % 3, accNh);
    __builtin_amdgcn_sched_barrier(0);
    __builtin_amdgcn_s_barrier();
  }

  // ---- epilogue: gates + state update (per-mf rollout decode; 96-row tiles span n) ----
#pragma unroll
  for (int mf = 0; mf < 3; ++mf) {
    const int mbase = m0 + wm * 48 + mf * 16 + kgrp * 4;
    const int n = mbase >> 8;
    const int k0 = Kmat[n * 4 + 0], k1 = Kmat[n * 4 + 1];
    const int k2 = Kmat[n * 4 + 2], k3 = Kmat[n * 4 + 3];
#pragma unroll
    for (int ii = 0; ii < 4; ++ii) {
      const int m = mbase + ii;
      float rg = sigm(accR[mf][ii] + br);
      float zg = sigm(accZ[mf][ii] + bz);
      float ng = tanhf(accNi[mf][ii] + bin + rg * (accNh[mf][ii] + bhn));
      float hp = (float)hin[(size_t)m * 1024 + jlane];
      float hnew = (1.0f - zg) * ng + zg * hp;
      bf16 hb = (bf16)hnew;
      hout[(size_t)m * 1024 + jlane] = hb;
      const int b = m & 255;
      if (k0 == step) states[((size_t)(n * 4 + 0) * 256 + b) * 1024 + jlane] = hb;
      if (k1 == step) states[((size_t)(n * 4 + 1) * 256 + b) * 1024 + jlane] = hb;
      if (k2 == step) states[((size_t)(n * 4 + 2) * 256 + b) * 1024 + jlane] = hb;
      if (k3 == step) states[((size_t)(n * 4 + 3) * 256 + b) * 1024 + jlane] = hb;
    }
  }
}

// ---------------- generic GEMM: C = A(M x K) @ W(N x K)^T, fused epilogues ----------------
template <int EPI>
__global__ __launch_bounds__(256) void k_gemm_epi(
    const bf16* __restrict__ A, const bf16* __restrict__ W, int K, int Nreal, int ld_out,
    const float* __restrict__ bias, const bf16* __restrict__ resid,
    float* __restrict__ outF, bf16* __restrict__ outB) {
  const int m0 = blockIdx.x * 64;
  const int j0 = blockIdx.y * 64;
  const int tid = threadIdx.x, wave = tid >> 6, lane = tid & 63;
  __shared__ alignas(16) bf16 Al[64][72];
  __shared__ alignas(16) bf16 Wl[64][72];

  f32x4 acc[4];
  const f32x4 zero = {0.f, 0.f, 0.f, 0.f};
#pragma unroll
  for (int f = 0; f < 4; ++f) acc[f] = zero;

  const int r = tid >> 3, c8 = (tid & 7) << 3;
  const int arow = wave * 16 + (lane & 15);
  const int koff = (lane >> 4) << 3;

  for (int kb = 0; kb < K; kb += 64) {
    *(bf16x8*)&Al[r][c8]      = *(const bf16x8*)&A[(size_t)(m0 + r) * K + kb + c8];
    *(bf16x8*)&Al[r + 32][c8] = *(const bf16x8*)&A[(size_t)(m0 + r + 32) * K + kb + c8];
    int jr = j0 + r;      if (jr >= Nreal) jr = Nreal - 1;
    int jr2 = j0 + r + 32; if (jr2 >= Nreal) jr2 = Nreal - 1;
    *(bf16x8*)&Wl[r][c8]      = *(const bf16x8*)&W[(size_t)jr * K + kb + c8];
    *(bf16x8*)&Wl[r + 32][c8] = *(const bf16x8*)&W[(size_t)jr2 * K + kb + c8];
    __syncthreads();
#pragma unroll
    for (int kk = 0; kk < 64; kk += 32) {
      bf16x8 av = *(const bf16x8*)&Al[arow][kk + koff];
#pragma unroll
      for (int nf = 0; nf < 4; ++nf) {
        acc[nf] = MFMA(av, *(const bf16x8*)&Wl[nf * 16 + (lane & 15)][kk + koff], acc[nf]);
      }
    }
    __syncthreads();
  }

#pragma unroll
  for (int nf = 0; nf < 4; ++nf) {
    int j = j0 + nf * 16 + (lane & 15);
    float bj = (j < Nreal) ? bias[j] : 0.f;
#pragma unroll
    for (int i = 0; i < 4; ++i) {
      int m = m0 + wave * 16 + ((lane >> 4) << 2) + i;
      float v = acc[nf][i] + bj;
      if (EPI == 0) {
        outB[(size_t)m * ld_out + j] = (bf16)fmaxf(v, 0.f);
      } else if (EPI == 1) {
        v = fmaxf(v, 0.f) + (float)resid[(size_t)m * ld_out + j];
        outB[(size_t)m * ld_out + j] = (bf16)v;
      } else {
        if (j < Nreal) outF[(size_t)m * ld_out + j] = v;
      }
    }
  }
}

// ---------------- loss ----------------
__global__ __launch_bounds__(256) void k_loss_rows(
    const float* __restrict__ logits, const float* __restrict__ obs,
    const int* __restrict__ idx_i, const int* __restrict__ Kmat,
    float* __restrict__ partials) {
  const int row = blockIdx.x;
  const int n = row >> 10, g = (row >> 8) & 3, b = row & 255;
  const int i = idx_i[n], k = Kmat[n * 4 + g];
  const float* L = logits + (size_t)row * 814;
  const float* ob = obs + ((size_t)(k + i + 1) * 256 + b) * 16;
  const int tid = threadIdx.x, lane = tid & 63, wv = tid >> 6;
  __shared__ float red[4];

  float total = 0.f;
#pragma unroll
  for (int p = 0; p < 2; ++p) {
    const float* Lp = L + p * 407;
    const float* tg = ob + p * 8;
    float mx = -1e30f;
    for (int c = tid; c < 400; c += 256) mx = fmaxf(mx, Lp[c]);
#pragma unroll
    for (int s = 32; s; s >>= 1) mx = fmaxf(mx, __shfl_xor(mx, s));
    __syncthreads();
    if (lane == 0) red[wv] = mx;
    __syncthreads();
    mx = fmaxf(fmaxf(red[0], red[1]), fmaxf(red[2], red[3]));
    __syncthreads();
    float se = 0.f;
    for (int c = tid; c < 400; c += 256) se += __expf(Lp[c] - mx);
#pragma unroll
    for (int s = 32; s; s >>= 1) se += __shfl_xor(se, s);
    if (lane == 0) red[wv] = se;
    __syncthreads();
    se = red[0] + red[1] + red[2] + red[3];
    __syncthreads();

    if (tid == 0) {
      int cls = (int)tg[0];
      float lse = mx + logf(se);
      float v = lse - Lp[cls];
      float d0 = Lp[400] - tg[1], d1 = Lp[401] - tg[2];
      v += 0.5f * (d0 * d0 + d1 * d1);
      float s2 = softplus_(Lp[402]) - tg[3]; v += s2 * s2;
      float s3 = softplus_(Lp[403]) - tg[4]; v += s3 * s3;
      v += softplus_(Lp[404]) - Lp[404] * tg[5];
      v += softplus_(Lp[405]) - Lp[405] * tg[6];
      v += softplus_(Lp[406]) - Lp[406] * tg[7];
      total += v;
    }
    __syncthreads();
  }
  if (tid == 0) partials[row] = total * (1.0f / 1024.0f);
}

__global__ void k_reduce_final(const float* __restrict__ partials, float* __restrict__ out) {
  __shared__ float s[256];
  float v = 0.f;
  for (int i = threadIdx.x; i < 6144; i += 256) v += partials[i];
  s[threadIdx.x] = v;
  __syncthreads();
  for (int st = 128; st; st >>= 1) {
    if (threadIdx.x < st) s[threadIdx.x] += s[threadIdx.x + st];
    __syncthreads();
  }
  if (threadIdx.x == 0) out[0] = s[0];
}

// ---------------- launcher ----------------

extern "C" void kernel_launch(void* const* d_in, const int* in_sizes, int n_in,
                              void* d_out, int out_size, void* d_ws, size_t ws_size,
                              hipStream_t stream) {
  const float* obs      = (const float*)d_in[0];
  const float* actions  = (const float*)d_in[1];
  const float* beliefs  = (const float*)d_in[2];
  const float* w_ih     = (const float*)d_in[3];
  const float* w_hh     = (const float*)d_in[4];
  const float* b_ih     = (const float*)d_in[5];
  const float* b_hh     = (const float*)d_in[6];
  const float* pre_w1   = (const float*)d_in[7];
  const float* pre_b1   = (const float*)d_in[8];
  const float* pre_w2   = (const float*)d_in[9];
  const float* pre_b2   = (const float*)d_in[10];
  const float* dec_w    = (const float*)d_in[11];
  const float* dec_b    = (const float*)d_in[12];
  const int*   idx_i    = (const int*)d_in[13];
  const int*   Kmat     = (const int*)d_in[14];
  float* outF = (float*)d_out;

  char* p = (char*)d_ws;
  auto carve = [&](size_t bytes) {
    char* q = p;
    p += (bytes + 255) & ~(size_t)255;
    return q;
  };
  bf16* Wh      = (bf16*)carve(3072u * 1024u * 2u);
  bf16* Wi      = (bf16*)carve(3072u * 64u * 2u);
  bf16* actBv   = (bf16*)carve(128u * 256u * 64u * 2u);
  bf16* preW1b  = (bf16*)carve(64u * 1024u * 2u);
  bf16* preW2b  = (bf16*)carve(1024u * 64u * 2u);
  bf16* decWb   = (bf16*)carve(814u * 1024u * 2u);
  bf16* hA      = (bf16*)carve(1536u * 1024u * 2u);
  bf16* hB      = (bf16*)carve(1536u * 1024u * 2u);
  bf16* states  = (bf16*)carve(6144u * 1024u * 2u);
  bf16* h1      = (bf16*)carve(6144u * 64u * 2u);
  bf16* xbuf    = (bf16*)carve(6144u * 1024u * 2u);
  float* logits = (float*)carve((size_t)6144u * 814u * 4u);
  float* partials = (float*)carve(6144u * 4u);

  auto cvt = [&](const float* src, bf16* dst, int n) {
    int grid = (n + 255) / 256;
    if (grid > 4096) grid = 4096;
    k_f32_to_bf16<<<grid, 256, 0, stream>>>(src, dst, n);
  };
  cvt(w_hh, Wh, 3072 * 1024);
  cvt(w_ih, Wi, 3072 * 64);
  cvt(actions, actBv, 128 * 256 * 64);
  cvt(pre_w1, preW1b, 64 * 1024);
  cvt(pre_w2, preW2b, 1024 * 64);
  cvt(dec_w, decWb, 814 * 1024);

  k_init_h<<<6144, 256, 0, stream>>>(beliefs, idx_i, hA);

  for (int t = 0; t < 30; ++t) {
    const bf16* hi = (t & 1) ? hB : hA;
    bf16* ho = (t & 1) ? hA : hB;
    k_gru_step<<<512, 256, 0, stream>>>(hi, ho, Wh, Wi, actBv, b_ih, b_hh,
                                        idx_i, Kmat, states, t);
  }

  k_gemm_epi<0><<<dim3(96, 1), 256, 0, stream>>>(states, preW1b, 1024, 64, 64,
                                                 pre_b1, nullptr, nullptr, h1);
  k_gemm_epi<1><<<dim3(96, 16), 256, 0, stream>>>(h1, preW2b, 64, 1024, 1024,
                                                  pre_b2, states, nullptr, xbuf);
  k_gemm_epi<2><<<dim3(96, 13), 256, 0, stream>>>(xbuf, decWb, 1024, 814, 814,
                                                  dec_b, nullptr, logits, nullptr);

  k_loss_rows<<<6144, 256, 0, stream>>>(logits, obs, idx_i, Kmat, partials);
  k_reduce_final<<<1, 256, 0, stream>>>(partials, outF);
}

// Round 6
// 662.398 us; speedup vs baseline: 4.3210x; 1.1138x over previous
//
#include <hip/hip_runtime.h>
#include <hip/hip_bf16.h>

typedef __bf16 bf16;
typedef __attribute__((ext_vector_type(4))) __bf16 bf16x4;
typedef __attribute__((ext_vector_type(8))) __bf16 bf16x8;
typedef __attribute__((ext_vector_type(4))) float f32x4;

static __device__ __forceinline__ f32x4 MFMA(bf16x8 a, bf16x8 b, f32x4 c) {
  return __builtin_amdgcn_mfma_f32_16x16x32_bf16(a, b, c, 0, 0, 0);
}

__device__ __forceinline__ float sigm(float x) { return 1.0f / (1.0f + __expf(-x)); }
__device__ __forceinline__ float softplus_(float x) {
  return fmaxf(x, 0.0f) + log1pf(__expf(-fabsf(x)));
}

__device__ __forceinline__ void gl16(const bf16* g, char* l) {
  __builtin_amdgcn_global_load_lds(
      (const __attribute__((address_space(1))) char*)g,
      (__attribute__((address_space(3))) char*)l, 16, 0, 0);
}

// ---------------- fused prep: all f32->bf16 conversions + h0 init ----------------
__global__ void k_prep(const float* __restrict__ whh, const float* __restrict__ wih,
                       const float* __restrict__ act, const float* __restrict__ w1,
                       const float* __restrict__ w2, const float* __restrict__ dw,
                       const float* __restrict__ beliefs, const int* __restrict__ idx_i,
                       bf16* __restrict__ Whd, bf16* __restrict__ Wid,
                       bf16* __restrict__ actd, bf16* __restrict__ w1d,
                       bf16* __restrict__ w2d, bf16* __restrict__ dwd,
                       bf16* __restrict__ hAd) {
  // quad (float4) boundaries, cumulative
  for (int q = blockIdx.x * blockDim.x + threadIdx.x; q < 1994240;
       q += gridDim.x * blockDim.x) {
    const float* src;
    bf16* dst;
    int off;
    if (q < 786432)       { src = whh; dst = Whd;  off = q; }
    else if (q < 835584)  { src = wih; dst = Wid;  off = q - 786432; }
    else if (q < 1359872) { src = act; dst = actd; off = q - 835584; }
    else if (q < 1376256) { src = w1;  dst = w1d;  off = q - 1359872; }
    else if (q < 1392640) { src = w2;  dst = w2d;  off = q - 1376256; }
    else if (q < 1601024) { src = dw;  dst = dwd;  off = q - 1392640; }
    else {
      const int e = (q - 1601024) << 2;
      const int n = e >> 18, rest = e & 262143;
      float4 v = *(const float4*)&beliefs[((size_t)idx_i[n] << 18) + rest];
      bf16x4 o = {(bf16)v.x, (bf16)v.y, (bf16)v.z, (bf16)v.w};
      *(bf16x4*)&hAd[e] = o;
      continue;
    }
    float4 v = *(const float4*)&src[(size_t)off << 2];
    bf16x4 o = {(bf16)v.x, (bf16)v.y, (bf16)v.z, (bf16)v.w};
    *(bf16x4*)&dst[(size_t)off << 2] = o;
  }
}

// ---------------- GRU step v5: v4 internals, Rg=2 x Cg=4 XCD layout ----------------
// XCD (rg,cg): rows 768*rg..+767, j-cols 256*cg..+255. Per-XCD L2 set:
// h-half 1.5MB + Wh-quarter 1.6MB <= 4MB. Cross-step L3 h-traffic halves vs Cg=8.
__global__ __launch_bounds__(256, 2) void k_gru_step(
    const bf16* __restrict__ hin, bf16* __restrict__ hout,
    const bf16* __restrict__ Wh, const bf16* __restrict__ Wi,
    const bf16* __restrict__ actB,
    const float* __restrict__ b_ih, const float* __restrict__ b_hh,
    const int* __restrict__ idx_i, const int* __restrict__ Kmat,
    bf16* __restrict__ states, int step) {
  const int pid = blockIdx.x;
  const int xcd = pid & 7;
  const int rg = xcd >> 2;        // row-group 0..1
  const int cgp = xcd & 3;        // col-group 0..3
  const int q = pid >> 3;         // 0..63
  const int mtl = q & 7;          // 0..7 within row-group
  const int jtl = q >> 3;         // 0..7 within col-group
  const int m0 = rg * 768 + mtl * 96;
  const int j0 = (cgp * 8 + jtl) * 32;

  const int tid = threadIdx.x, wave = tid >> 6, lane = tid & 63;
  const int l15 = lane & 15;
  const int kgrp = lane >> 4;     // 0..3
  const int wm = wave >> 1;       // 0..1 : row half (48)
  const int wj = wave & 1;        // 0..1 : j half (16)
  const int jlane = j0 + wj * 16 + l15;

  __shared__ alignas(16) bf16 As[3][96][64];   // 3 x 12 KB
  __shared__ alignas(16) bf16 Bs[3][96][64];   // 3 x 12 KB  (rows = g*32 + jj)

  const int srow = lane >> 3;                      // 0..7
  const int scol = (((lane & 7) ^ srow) << 3);     // pre-swizzled source col (elems)

  const bf16* asrc[3];
  const bf16* bsrc[3];
  const bf16* aisrc[3];
  const bf16* bisrc[3];
#pragma unroll
  for (int i = 0; i < 3; ++i) {
    const int prow = wave * 24 + i * 8 + srow;     // 0..95
    const int grow = m0 + prow;
    asrc[i] = hin + (size_t)grow * 1024 + scol;
    const int wr = (prow >> 5) * 1024 + j0 + (prow & 31);
    bsrc[i] = Wh + (size_t)wr * 1024 + scol;
    bisrc[i] = Wi + (size_t)wr * 64 + scol;
    const int np = grow >> 8;
    aisrc[i] = actB + ((size_t)(idx_i[np] + step) * 256 + (grow & 255)) * 64 + scol;
  }

  auto stage = [&](int buf, int it) {
    char* ad = (char*)As + buf * 12288 + (wave * 24) * 128;
    char* bd = (char*)Bs + buf * 12288 + (wave * 24) * 128;
    if (it < 16) {
#pragma unroll
      for (int i = 0; i < 3; ++i) {
        gl16(asrc[i] + it * 64, ad + i * 1024);
        gl16(bsrc[i] + it * 64, bd + i * 1024);
      }
    } else {
#pragma unroll
      for (int i = 0; i < 3; ++i) {
        gl16(aisrc[i], ad + i * 1024);
        gl16(bisrc[i], bd + i * 1024);
      }
    }
  };

  f32x4 accR[3], accZ[3], accNh[3], accNi[3];
  const f32x4 zero = {0.f, 0.f, 0.f, 0.f};
#pragma unroll
  for (int f = 0; f < 3; ++f) { accR[f] = zero; accZ[f] = zero; accNh[f] = zero; accNi[f] = zero; }

  const float br = b_ih[jlane] + b_hh[jlane];
  const float bz = b_ih[1024 + jlane] + b_hh[1024 + jlane];
  const float bin = b_ih[2048 + jlane];
  const float bhn = b_hh[2048 + jlane];

  auto compute = [&](int buf, f32x4 (&gN)[3]) {
    const char* ab = (const char*)As + buf * 12288;
    const char* bb = (const char*)Bs + buf * 12288;
#pragma unroll
    for (int kkI = 0; kkI < 2; ++kkI) {
      const int kbyte = (((kkI << 5) + (kgrp << 3)) << 1) ^ ((l15 & 7) << 4);
      bf16x8 a0 = *(const bf16x8*)(ab + (wm * 48 + l15) * 128 + kbyte);
      bf16x8 a1 = *(const bf16x8*)(ab + (wm * 48 + 16 + l15) * 128 + kbyte);
      bf16x8 a2 = *(const bf16x8*)(ab + (wm * 48 + 32 + l15) * 128 + kbyte);
      bf16x8 b_r = *(const bf16x8*)(bb + (wj * 16 + l15) * 128 + kbyte);
      bf16x8 b_z = *(const bf16x8*)(bb + (32 + wj * 16 + l15) * 128 + kbyte);
      bf16x8 b_n = *(const bf16x8*)(bb + (64 + wj * 16 + l15) * 128 + kbyte);
      accR[0] = MFMA(a0, b_r, accR[0]);
      accR[1] = MFMA(a1, b_r, accR[1]);
      accR[2] = MFMA(a2, b_r, accR[2]);
      accZ[0] = MFMA(a0, b_z, accZ[0]);
      accZ[1] = MFMA(a1, b_z, accZ[1]);
      accZ[2] = MFMA(a2, b_z, accZ[2]);
      gN[0] = MFMA(a0, b_n, gN[0]);
      gN[1] = MFMA(a1, b_n, gN[1]);
      gN[2] = MFMA(a2, b_n, gN[2]);
    }
  };

  stage(0, 0);
  stage(1, 1);

#pragma unroll
  for (int t = 0; t < 17; ++t) {
    if (t < 15) stage((t + 2) % 3, t + 2);
    if (t < 15)       asm volatile("s_waitcnt vmcnt(12)" ::: "memory");
    else if (t == 15) asm volatile("s_waitcnt vmcnt(6)" ::: "memory");
    else              asm volatile("s_waitcnt vmcnt(0)" ::: "memory");
    __builtin_amdgcn_s_barrier();
    if (t == 16) compute(16 % 3, accNi);
    else         compute(t % 3, accNh);
    __builtin_amdgcn_sched_barrier(0);
    __builtin_amdgcn_s_barrier();
  }

  // ---- epilogue ----
#pragma unroll
  for (int mf = 0; mf < 3; ++mf) {
    const int mbase = m0 + wm * 48 + mf * 16 + kgrp * 4;
    const int n = mbase >> 8;
    const int k0 = Kmat[n * 4 + 0], k1 = Kmat[n * 4 + 1];
    const int k2 = Kmat[n * 4 + 2], k3 = Kmat[n * 4 + 3];
#pragma unroll
    for (int ii = 0; ii < 4; ++ii) {
      const int m = mbase + ii;
      float rg2 = sigm(accR[mf][ii] + br);
      float zg = sigm(accZ[mf][ii] + bz);
      float ng = tanhf(accNi[mf][ii] + bin + rg2 * (accNh[mf][ii] + bhn));
      float hp = (float)hin[(size_t)m * 1024 + jlane];
      float hnew = (1.0f - zg) * ng + zg * hp;
      bf16 hb = (bf16)hnew;
      hout[(size_t)m * 1024 + jlane] = hb;
      const int b = m & 255;
      if (k0 == step) states[((size_t)(n * 4 + 0) * 256 + b) * 1024 + jlane] = hb;
      if (k1 == step) states[((size_t)(n * 4 + 1) * 256 + b) * 1024 + jlane] = hb;
      if (k2 == step) states[((size_t)(n * 4 + 2) * 256 + b) * 1024 + jlane] = hb;
      if (k3 == step) states[((size_t)(n * 4 + 3) * 256 + b) * 1024 + jlane] = hb;
    }
  }
}

// ---------------- generic GEMM: C = A(M x K) @ W(N x K)^T, fused epilogues ----------------
// SWZ: linear grid; XCD x owns mt-chunk [12x,12x+12) x all jt -> A-chunk + W L2-resident.
template <int EPI, int SWZ>
__global__ __launch_bounds__(256) void k_gemm_epi(
    const bf16* __restrict__ A, const bf16* __restrict__ W, int K, int Nreal, int ld_out,
    const float* __restrict__ bias, const bf16* __restrict__ resid,
    float* __restrict__ outF, bf16* __restrict__ outB) {
  int mt, jt;
  if (SWZ) {
    const int lin = blockIdx.x;
    const int x = lin & 7, k = lin >> 3;
    mt = 12 * x + k % 12;
    jt = k / 12;
  } else {
    mt = blockIdx.x;
    jt = blockIdx.y;
  }
  const int m0 = mt * 64;
  const int j0 = jt * 64;
  const int tid = threadIdx.x, wave = tid >> 6, lane = tid & 63;
  __shared__ alignas(16) bf16 Al[64][72];
  __shared__ alignas(16) bf16 Wl[64][72];

  f32x4 acc[4];
  const f32x4 zero = {0.f, 0.f, 0.f, 0.f};
#pragma unroll
  for (int f = 0; f < 4; ++f) acc[f] = zero;

  const int r = tid >> 3, c8 = (tid & 7) << 3;
  const int arow = wave * 16 + (lane & 15);
  const int koff = (lane >> 4) << 3;

  for (int kb = 0; kb < K; kb += 64) {
    *(bf16x8*)&Al[r][c8]      = *(const bf16x8*)&A[(size_t)(m0 + r) * K + kb + c8];
    *(bf16x8*)&Al[r + 32][c8] = *(const bf16x8*)&A[(size_t)(m0 + r + 32) * K + kb + c8];
    int jr = j0 + r;      if (jr >= Nreal) jr = Nreal - 1;
    int jr2 = j0 + r + 32; if (jr2 >= Nreal) jr2 = Nreal - 1;
    *(bf16x8*)&Wl[r][c8]      = *(const bf16x8*)&W[(size_t)jr * K + kb + c8];
    *(bf16x8*)&Wl[r + 32][c8] = *(const bf16x8*)&W[(size_t)jr2 * K + kb + c8];
    __syncthreads();
#pragma unroll
    for (int kk = 0; kk < 64; kk += 32) {
      bf16x8 av = *(const bf16x8*)&Al[arow][kk + koff];
#pragma unroll
      for (int nf = 0; nf < 4; ++nf) {
        acc[nf] = MFMA(av, *(const bf16x8*)&Wl[nf * 16 + (lane & 15)][kk + koff], acc[nf]);
      }
    }
    __syncthreads();
  }

#pragma unroll
  for (int nf = 0; nf < 4; ++nf) {
    int j = j0 + nf * 16 + (lane & 15);
    float bj = (j < Nreal) ? bias[j] : 0.f;
#pragma unroll
    for (int i = 0; i < 4; ++i) {
      int m = m0 + wave * 16 + ((lane >> 4) << 2) + i;
      float v = acc[nf][i] + bj;
      if (EPI == 0) {
        outB[(size_t)m * ld_out + j] = (bf16)fmaxf(v, 0.f);
      } else if (EPI == 1) {
        v = fmaxf(v, 0.f) + (float)resid[(size_t)m * ld_out + j];
        outB[(size_t)m * ld_out + j] = (bf16)v;
      } else {
        if (j < Nreal) outF[(size_t)m * ld_out + j] = v;
      }
    }
  }
}

// ---------------- loss ----------------
__global__ __launch_bounds__(256) void k_loss_rows(
    const float* __restrict__ logits, const float* __restrict__ obs,
    const int* __restrict__ idx_i, const int* __restrict__ Kmat,
    float* __restrict__ partials) {
  const int row = blockIdx.x;
  const int n = row >> 10, g = (row >> 8) & 3, b = row & 255;
  const int i = idx_i[n], k = Kmat[n * 4 + g];
  const float* L = logits + (size_t)row * 814;
  const float* ob = obs + ((size_t)(k + i + 1) * 256 + b) * 16;
  const int tid = threadIdx.x, lane = tid & 63, wv = tid >> 6;
  __shared__ float red[4];

  float total = 0.f;
#pragma unroll
  for (int p = 0; p < 2; ++p) {
    const float* Lp = L + p * 407;
    const float* tg = ob + p * 8;
    float mx = -1e30f;
    for (int c = tid; c < 400; c += 256) mx = fmaxf(mx, Lp[c]);
#pragma unroll
    for (int s = 32; s; s >>= 1) mx = fmaxf(mx, __shfl_xor(mx, s));
    __syncthreads();
    if (lane == 0) red[wv] = mx;
    __syncthreads();
    mx = fmaxf(fmaxf(red[0], red[1]), fmaxf(red[2], red[3]));
    __syncthreads();
    float se = 0.f;
    for (int c = tid; c < 400; c += 256) se += __expf(Lp[c] - mx);
#pragma unroll
    for (int s = 32; s; s >>= 1) se += __shfl_xor(se, s);
    if (lane == 0) red[wv] = se;
    __syncthreads();
    se = red[0] + red[1] + red[2] + red[3];
    __syncthreads();

    if (tid == 0) {
      int cls = (int)tg[0];
      float lse = mx + logf(se);
      float v = lse - Lp[cls];
      float d0 = Lp[400] - tg[1], d1 = Lp[401] - tg[2];
      v += 0.5f * (d0 * d0 + d1 * d1);
      float s2 = softplus_(Lp[402]) - tg[3]; v += s2 * s2;
      float s3 = softplus_(Lp[403]) - tg[4]; v += s3 * s3;
      v += softplus_(Lp[404]) - Lp[404] * tg[5];
      v += softplus_(Lp[405]) - Lp[405] * tg[6];
      v += softplus_(Lp[406]) - Lp[406] * tg[7];
      total += v;
    }
    __syncthreads();
  }
  if (tid == 0) partials[row] = total * (1.0f / 1024.0f);
}

__global__ void k_reduce_final(const float* __restrict__ partials, float* __restrict__ out) {
  __shared__ float s[256];
  float v = 0.f;
  for (int i = threadIdx.x; i < 6144; i += 256) v += partials[i];
  s[threadIdx.x] = v;
  __syncthreads();
  for (int st = 128; st; st >>= 1) {
    if (threadIdx.x < st) s[threadIdx.x] += s[threadIdx.x + st];
    __syncthreads();
  }
  if (threadIdx.x == 0) out[0] = s[0];
}

// ---------------- launcher ----------------

extern "C" void kernel_launch(void* const* d_in, const int* in_sizes, int n_in,
                              void* d_out, int out_size, void* d_ws, size_t ws_size,
                              hipStream_t stream) {
  const float* obs      = (const float*)d_in[0];
  const float* actions  = (const float*)d_in[1];
  const float* beliefs  = (const float*)d_in[2];
  const float* w_ih     = (const float*)d_in[3];
  const float* w_hh     = (const float*)d_in[4];
  const float* b_ih     = (const float*)d_in[5];
  const float* b_hh     = (const float*)d_in[6];
  const float* pre_w1   = (const float*)d_in[7];
  const float* pre_b1   = (const float*)d_in[8];
  const float* pre_w2   = (const float*)d_in[9];
  const float* pre_b2   = (const float*)d_in[10];
  const float* dec_w    = (const float*)d_in[11];
  const float* dec_b    = (const float*)d_in[12];
  const int*   idx_i    = (const int*)d_in[13];
  const int*   Kmat     = (const int*)d_in[14];
  float* outF = (float*)d_out;

  char* p = (char*)d_ws;
  auto carve = [&](size_t bytes) {
    char* q = p;
    p += (bytes + 255) & ~(size_t)255;
    return q;
  };
  bf16* Wh      = (bf16*)carve(3072u * 1024u * 2u);
  bf16* Wi      = (bf16*)carve(3072u * 64u * 2u);
  bf16* actBv   = (bf16*)carve(128u * 256u * 64u * 2u);
  bf16* preW1b  = (bf16*)carve(64u * 1024u * 2u);
  bf16* preW2b  = (bf16*)carve(1024u * 64u * 2u);
  bf16* decWb   = (bf16*)carve(814u * 1024u * 2u);
  bf16* hA      = (bf16*)carve(1536u * 1024u * 2u);
  bf16* hB      = (bf16*)carve(1536u * 1024u * 2u);
  bf16* states  = (bf16*)carve(6144u * 1024u * 2u);
  bf16* h1      = (bf16*)carve(6144u * 64u * 2u);
  bf16* xbuf    = (bf16*)carve(6144u * 1024u * 2u);
  float* logits = (float*)carve((size_t)6144u * 814u * 4u);
  float* partials = (float*)carve(6144u * 4u);

  k_prep<<<2048, 256, 0, stream>>>(w_hh, w_ih, actions, pre_w1, pre_w2, dec_w,
                                   beliefs, idx_i, Wh, Wi, actBv, preW1b, preW2b,
                                   decWb, hA);

  for (int t = 0; t < 30; ++t) {
    const bf16* hi = (t & 1) ? hB : hA;
    bf16* ho = (t & 1) ? hA : hB;
    k_gru_step<<<512, 256, 0, stream>>>(hi, ho, Wh, Wi, actBv, b_ih, b_hh,
                                        idx_i, Kmat, states, t);
  }

  k_gemm_epi<0, 0><<<dim3(96, 1), 256, 0, stream>>>(states, preW1b, 1024, 64, 64,
                                                    pre_b1, nullptr, nullptr, h1);
  k_gemm_epi<1, 1><<<1536, 256, 0, stream>>>(h1, preW2b, 64, 1024, 1024,
                                             pre_b2, states, nullptr, xbuf);
  k_gemm_epi<2, 1><<<1248, 256, 0, stream>>>(xbuf, decWb, 1024, 814, 814,
                                             dec_b, nullptr, logits, nullptr);

  k_loss_rows<<<6144, 256, 0, stream>>>(logits, obs, idx_i, Kmat, partials);
  k_reduce_final<<<1, 256, 0, stream>>>(partials, outF);
}